// Round 8
// baseline (101.612 us; speedup 1.0000x reference)
//
#include <hip/hip_runtime.h>
#include <hip/hip_bf16.h>

#define BATCH 16384
#define NF    512
#define DEG   8
#define NC    10
#define KB    8

#define RB     16                // rows per block (one MFMA tile)
#define PITCH2 520               // ushort pitch: 520*2B=1040B=260 dwords (even ->
                                 // 2-way column aliasing, free per m136); %8==0
                                 // keeps 16B alignment for ds_read_b128
#define NT     512               // 8 waves; wave w owns features [w*64, w*64+64)
#define NWAVES 8

#define CBN (NC * NF * KB)       // 40960 packed coeff elems
#define BBN (NC * NF)            // 5120 packed base elems

#define INV2PI 0.15915494309189535f
#define LOG2E  1.4426950408889634f

typedef __attribute__((ext_vector_type(2))) float v2f;             // v_pk_*_f32
typedef __attribute__((ext_vector_type(8))) short bfrag;           // 8 bf16
typedef __attribute__((ext_vector_type(8))) unsigned short us8;    // LDS b128
typedef __attribute__((ext_vector_type(4))) float f32x4;           // MFMA C/D

union frag_u { bfrag s; unsigned u[4]; };

__device__ __forceinline__ v2f v2fma(v2f a, v2f b, v2f c) {
    return __builtin_elementwise_fma(a, b, c);
}
__device__ __forceinline__ v2f v2exp(v2f x) {              // e^x
    v2f a = x * LOG2E;
    v2f r; r.x = __builtin_amdgcn_exp2f(a.x); r.y = __builtin_amdgcn_exp2f(a.y);
    return r;
}
__device__ __forceinline__ v2f v2rcp(v2f x) {
    v2f r; r.x = __builtin_amdgcn_rcpf(x.x); r.y = __builtin_amdgcn_rcpf(x.y);
    return r;
}
__device__ __forceinline__ v2f v2sin2pi(v2f x) {           // sin(2*pi*x)
    v2f r; r.x = __builtin_amdgcn_sinf(x.x); r.y = __builtin_amdgcn_sinf(x.y);
    return r;
}
// 0.99*tanh(x) = 0.99 - 1.98/(exp(2x)+1)
__device__ __forceinline__ v2f v2tanh99(v2f x) {
    v2f e = v2exp(x + x);
    v2f r = v2rcp(e + 1.0f);
    return v2fma(r, (v2f)(-1.98f), (v2f)(0.99f));
}
// silu(v) = v / (1 + exp(-v)), packed
__device__ __forceinline__ v2f v2silu(v2f v) {
    v2f e = v2exp(-v);
    v2f r = v2rcp(e + 1.0f);
    return v * r;
}
// f32 pair -> packed bf16 (v_cvt_pk_bf16_f32), lo in low 16 bits
__device__ __forceinline__ unsigned cvtpk2(float lo, float hi) {
    __hip_bfloat162 h = __float22bfloat162_rn(float2{lo, hi});
    unsigned u;
    __builtin_memcpy(&u, &h, sizeof(u));
    return u;
}
__device__ __forceinline__ float bf2f(unsigned short h) {
    unsigned u = ((unsigned)h) << 16;
    return __builtin_bit_cast(float, u);
}

// ---- prep: bf16-pack coeff (CBN) + base (BBN) into ws, every launch --------
__global__ __launch_bounds__(256) void prep_kernel(
    const float* __restrict__ coeff, const float* __restrict__ base,
    unsigned short* __restrict__ pk)
{
    const int i = blockIdx.x * 256 + threadIdx.x;
    if (i < CBN)
        pk[i] = (unsigned short)((__builtin_bit_cast(unsigned, coeff[i]) + 0x8000u) >> 16);
    else if (i < CBN + BBN)
        pk[i] = (unsigned short)((__builtin_bit_cast(unsigned, base[i - CBN]) + 0x8000u) >> 16);
}

__global__ __launch_bounds__(NT, 8) void qkan_kernel(
    const float* __restrict__ X,        // (B, F)
    const float* __restrict__ lcu_w,    // (F, DEG)
    const float* __restrict__ alpha,    // (F, DEG)
    const unsigned short* __restrict__ pk,  // bf16: coeff[CBN] then base[BBN]
    const float* __restrict__ bias,     // (C)
    float* __restrict__ out)            // (B, C)
{
    __shared__ unsigned short s_mem[RB * PITCH2];   // 16.6 KB: summed tile, bf16
    __shared__ float s_red[NWAVES * RB * 16];       // 8 KB: cross-wave partials

    const int t    = threadIdx.x;
    const int row0 = blockIdx.x * RB;

    // ---------------- phase 1: elementwise -> summed(b,f) into LDS ----------
    // 512 threads: thread owns feature pair (t&255)*2, row half (t>>8)*8.
    {
        const int fA = (t & 255) * 2;
        const int rh = (t >> 8) * 8;

        float wa[2][DEG], aa[2][DEG], den[2];
#pragma unroll
        for (int i = 0; i < 2; ++i) {
            const float4 w0 = *(const float4*)(lcu_w + (fA + i) * DEG);
            const float4 w1 = *(const float4*)(lcu_w + (fA + i) * DEG + 4);
            const float4 a0 = *(const float4*)(alpha + (fA + i) * DEG);
            const float4 a1 = *(const float4*)(alpha + (fA + i) * DEG + 4);
            wa[i][0]=w0.x; wa[i][1]=w0.y; wa[i][2]=w0.z; wa[i][3]=w0.w;
            wa[i][4]=w1.x; wa[i][5]=w1.y; wa[i][6]=w1.z; wa[i][7]=w1.w;
            aa[i][0]=a0.x; aa[i][1]=a0.y; aa[i][2]=a0.z; aa[i][3]=a0.w;
            aa[i][4]=a1.x; aa[i][5]=a1.y; aa[i][6]=a1.z; aa[i][7]=a1.w;
            float d = 1e-8f;
#pragma unroll
            for (int k = 0; k < DEG; ++k) d += fabsf(wa[i][k]);
            den[i] = d;
        }
        v2f W[DEG], A2[DEG];
#pragma unroll
        for (int d = 0; d < DEG; ++d) {
            W[d]  = (v2f){wa[0][d], wa[1][d]};
            A2[d] = (v2f){aa[0][d] * INV2PI, aa[1][d] * INV2PI};  // fold 1/2pi
        }
        const v2f rden = (v2f){__builtin_amdgcn_rcpf(den[0]),
                               __builtin_amdgcn_rcpf(den[1])};

#pragma unroll 4
        for (int r8 = 0; r8 < 8; ++r8) {
            const int r = rh + r8;
            const v2f xv = *(const v2f*)(X + (row0 + r) * NF + fA);
            const v2f x  = v2tanh99(xv);
            const v2f x2 = x + x;
            v2f tkm1 = (v2f){1.0f, 1.0f}, tk = x, num = (v2f){0.0f, 0.0f};
#pragma unroll
            for (int d = 0; d < DEG; ++d) {
                num = v2fma(W[d], tk, num);
                v2f tn = v2fma(x2, tk, -tkm1);
                tkm1 = tk; tk = tn;
            }
            const v2f lcu = num * rden;
            v2f ss = (v2f){0.0f, 0.0f};
#pragma unroll
            for (int d = 0; d < DEG; ++d)
                ss += v2sin2pi(lcu * A2[d]);
            const v2f sm = ss * 0.125f;
            *(unsigned*)(&s_mem[r * PITCH2 + fA]) = cvtpk2(sm.x, sm.y);
        }
    }
    __syncthreads();

    // ------------- phase 2: MFMA contraction; 8 waves split K ---------------
    const int lane = t & 63;
    const int wave = __builtin_amdgcn_readfirstlane(t >> 6);
    const int n    = lane & 15;          // class col (and A-row m)
    const int q    = lane >> 4;          // quad
    const int ncl  = (n < NC) ? n : (NC - 1);  // junk cols n>=10 never read back
    const int fw   = wave * 64;          // this wave's feature range

    const unsigned short* cb = pk;                          // coeff bf16
    const unsigned short* bb = pk + CBN;                    // base  bf16
    const unsigned short* cbase = cb + (ncl * NF + fw) * KB;

    f32x4 acc0 = {0.f, 0.f, 0.f, 0.f};
    f32x4 acc1 = {0.f, 0.f, 0.f, 0.f};

    // GEMM1: phi @ coeff^T over 64 features = 16 K-tiles, in pairs
#pragma unroll 4
    for (int kp = 0; kp < 8; ++kp) {
        const bfrag b0 = *(const bfrag*)(cbase + (kp * 8 + q) * KB);
        const bfrag b1 = *(const bfrag*)(cbase + (kp * 8 + 4 + q) * KB);

        const float sA = bf2f(s_mem[n * PITCH2 + fw + kp * 8 + q]);
        const float sB = bf2f(s_mem[n * PITCH2 + fw + kp * 8 + 4 + q]);
        const v2f s  = v2tanh99((v2f){sA, sB});
        const v2f s2 = s + s;
        v2f T[KB];
        {
            v2f tkm1 = (v2f){1.0f, 1.0f}, tk = s;
#pragma unroll
            for (int k = 0; k < KB; ++k) {
                T[k] = tk;
                v2f tn = v2fma(s2, tk, -tkm1);
                tkm1 = tk; tk = tn;
            }
        }
        frag_u fa0, fa1;
#pragma unroll
        for (int i = 0; i < 4; ++i) {
            fa0.u[i] = cvtpk2(T[2 * i].x, T[2 * i + 1].x);
            fa1.u[i] = cvtpk2(T[2 * i].y, T[2 * i + 1].y);
        }
        acc0 = __builtin_amdgcn_mfma_f32_16x16x32_bf16(fa0.s, b0, acc0, 0, 0, 0);
        acc1 = __builtin_amdgcn_mfma_f32_16x16x32_bf16(fa1.s, b1, acc1, 0, 0, 0);
    }

    // GEMM2: silu @ base^T over 64 features = 2 K-tiles
#pragma unroll
    for (int kt2 = 0; kt2 < 2; ++kt2) {
        const bfrag b = *(const bfrag*)(bb + ncl * NF + fw + kt2 * 32 + q * 8);
        const us8 sv = *(const us8*)(&s_mem[n * PITCH2 + fw + kt2 * 32 + q * 8]);
        v2f vv[4];
#pragma unroll
        for (int g = 0; g < 4; ++g)
            vv[g] = (v2f){bf2f(sv[2 * g]), bf2f(sv[2 * g + 1])};
        frag_u fa;
#pragma unroll
        for (int g = 0; g < 4; ++g) {
            const v2f sl = v2silu(vv[g]);
            fa.u[g] = cvtpk2(sl.x, sl.y);
        }
        if (kt2 & 1)
            acc1 = __builtin_amdgcn_mfma_f32_16x16x32_bf16(fa.s, b, acc1, 0, 0, 0);
        else
            acc0 = __builtin_amdgcn_mfma_f32_16x16x32_bf16(fa.s, b, acc0, 0, 0, 0);
    }

    // ------------- cross-wave K-reduction + store ---------------------------
    // D layout: row = q*4+i, col = n. Write all 16 cols; only c<10 read back.
    const f32x4 acc = acc0 + acc1;
#pragma unroll
    for (int i = 0; i < 4; ++i)
        s_red[wave * (RB * 16) + (q * 4 + i) * 16 + n] = acc[i];
    __syncthreads();

    if (t < RB * NC) {
        const int r = t / NC;
        const int c = t - r * NC;
        float v = bias[c];
#pragma unroll
        for (int w = 0; w < NWAVES; ++w)
            v += s_red[w * (RB * 16) + r * 16 + c];
        out[(row0 + r) * NC + c] = v;
    }
}

extern "C" void kernel_launch(void* const* d_in, const int* in_sizes, int n_in,
                              void* d_out, int out_size, void* d_ws, size_t ws_size,
                              hipStream_t stream) {
    const float* X      = (const float*)d_in[0];
    const float* lcu_w  = (const float*)d_in[1];
    const float* alpha  = (const float*)d_in[2];
    const float* coeff  = (const float*)d_in[3];
    const float* base   = (const float*)d_in[4];
    const float* bias   = (const float*)d_in[5];
    float* out = (float*)d_out;
    unsigned short* pk = (unsigned short*)d_ws;   // 92 KB bf16 tables

    prep_kernel<<<(CBN + BBN + 255) / 256, 256, 0, stream>>>(coeff, base, pk);
    qkan_kernel<<<BATCH / RB, NT, 0, stream>>>(X, lcu_w, alpha, pk, bias, out);
}

// Round 9
// 100.869 us; speedup vs baseline: 1.0074x; 1.0074x over previous
//
#include <hip/hip_runtime.h>
#include <hip/hip_bf16.h>

#define BATCH 16384
#define NF    512
#define DEG   8
#define NC    10
#define KB    8

#define RB     16                // rows per block (one MFMA tile)
#define PITCH2 520               // ushort pitch: 1040 B rows (16B-aligned)
#define NT     256               // 4 waves; wave w owns features [w*128, +128)
#define NWAVES 4

#define CBN (NC * NF * KB)       // 40960 packed coeff elems
#define BBN (NC * NF)            // 5120 packed base elems

#define INV2PI 0.15915494309189535f
#define LOG2E  1.4426950408889634f

typedef __attribute__((ext_vector_type(2))) float v2f;             // v_pk_*_f32
typedef __attribute__((ext_vector_type(8))) short bfrag;           // 8 bf16
typedef __attribute__((ext_vector_type(8))) unsigned short us8;    // LDS b128
typedef __attribute__((ext_vector_type(4))) float f32x4;           // MFMA C/D

union frag_u  { bfrag s; unsigned u[4]; };
union frag_u2 { us8 v; bfrag s; };

__device__ __forceinline__ v2f v2fma(v2f a, v2f b, v2f c) {
    return __builtin_elementwise_fma(a, b, c);
}
__device__ __forceinline__ v2f v2exp(v2f x) {              // e^x
    v2f a = x * LOG2E;
    v2f r; r.x = __builtin_amdgcn_exp2f(a.x); r.y = __builtin_amdgcn_exp2f(a.y);
    return r;
}
__device__ __forceinline__ v2f v2rcp(v2f x) {
    v2f r; r.x = __builtin_amdgcn_rcpf(x.x); r.y = __builtin_amdgcn_rcpf(x.y);
    return r;
}
__device__ __forceinline__ v2f v2sin2pi(v2f x) {           // sin(2*pi*x)
    v2f r; r.x = __builtin_amdgcn_sinf(x.x); r.y = __builtin_amdgcn_sinf(x.y);
    return r;
}
// 0.99*tanh(x) = 0.99 - 1.98/(exp(2x)+1)
__device__ __forceinline__ v2f v2tanh99(v2f x) {
    v2f e = v2exp(x + x);
    v2f r = v2rcp(e + 1.0f);
    return v2fma(r, (v2f)(-1.98f), (v2f)(0.99f));
}
// f32 pair -> packed bf16 (v_cvt_pk_bf16_f32), lo in low 16 bits
__device__ __forceinline__ unsigned cvtpk2(float lo, float hi) {
    __hip_bfloat162 h = __float22bfloat162_rn(float2{lo, hi});
    unsigned u;
    __builtin_memcpy(&u, &h, sizeof(u));
    return u;
}
__device__ __forceinline__ float bf2f(unsigned short h) {
    unsigned u = ((unsigned)h) << 16;
    return __builtin_bit_cast(float, u);
}

// ---- prep: bf16-pack coeff (CBN) + base (BBN) into ws, every launch --------
__global__ __launch_bounds__(256) void prep_kernel(
    const float* __restrict__ coeff, const float* __restrict__ base,
    unsigned short* __restrict__ pk)
{
    const int i = blockIdx.x * 256 + threadIdx.x;
    if (i < CBN)
        pk[i] = (unsigned short)((__builtin_bit_cast(unsigned, coeff[i]) + 0x8000u) >> 16);
    else if (i < CBN + BBN)
        pk[i] = (unsigned short)((__builtin_bit_cast(unsigned, base[i - CBN]) + 0x8000u) >> 16);
}

__global__ __launch_bounds__(NT, 4) void qkan_kernel(
    const float* __restrict__ X,        // (B, F)
    const float* __restrict__ lcu_w,    // (F, DEG)
    const float* __restrict__ alpha,    // (F, DEG)
    const unsigned short* __restrict__ pk,  // bf16: coeff[CBN] then base[BBN]
    const float* __restrict__ bias,     // (C)
    float* __restrict__ out)            // (B, C)
{
    __shared__ unsigned short s_s[RB * PITCH2];     // 16.6 KB: s = 0.99*tanh(summed)
    __shared__ unsigned short s_l[RB * PITCH2];     // 16.6 KB: silu(summed)
    __shared__ float s_red[NWAVES * RB * 16];       // 4 KB: cross-wave partials

    const int t    = threadIdx.x;
    const int row0 = blockIdx.x * RB;

    // ------- phase 1: elementwise -> s(b,f), silu(b,f) into LDS (bf16) ------
    // 256 threads: thread owns feature pair t*2, all 16 rows.
    {
        const int fA = t * 2;

        float wa[2][DEG], aa[2][DEG], den[2];
#pragma unroll
        for (int i = 0; i < 2; ++i) {
            const float4 w0 = *(const float4*)(lcu_w + (fA + i) * DEG);
            const float4 w1 = *(const float4*)(lcu_w + (fA + i) * DEG + 4);
            const float4 a0 = *(const float4*)(alpha + (fA + i) * DEG);
            const float4 a1 = *(const float4*)(alpha + (fA + i) * DEG + 4);
            wa[i][0]=w0.x; wa[i][1]=w0.y; wa[i][2]=w0.z; wa[i][3]=w0.w;
            wa[i][4]=w1.x; wa[i][5]=w1.y; wa[i][6]=w1.z; wa[i][7]=w1.w;
            aa[i][0]=a0.x; aa[i][1]=a0.y; aa[i][2]=a0.z; aa[i][3]=a0.w;
            aa[i][4]=a1.x; aa[i][5]=a1.y; aa[i][6]=a1.z; aa[i][7]=a1.w;
            float d = 1e-8f;
#pragma unroll
            for (int k = 0; k < DEG; ++k) d += fabsf(wa[i][k]);
            den[i] = d;
        }
        v2f W[DEG], A2[DEG];
#pragma unroll
        for (int d = 0; d < DEG; ++d) {
            W[d]  = (v2f){wa[0][d], wa[1][d]};
            A2[d] = (v2f){aa[0][d] * INV2PI, aa[1][d] * INV2PI};  // fold 1/2pi
        }
        const v2f rden = (v2f){__builtin_amdgcn_rcpf(den[0]),
                               __builtin_amdgcn_rcpf(den[1])};

#pragma unroll 4
        for (int r = 0; r < RB; ++r) {
            const v2f xv = *(const v2f*)(X + (row0 + r) * NF + fA);
            const v2f x  = v2tanh99(xv);
            const v2f x2 = x + x;
            v2f tkm1 = (v2f){1.0f, 1.0f}, tk = x, num = (v2f){0.0f, 0.0f};
#pragma unroll
            for (int d = 0; d < DEG; ++d) {
                num = v2fma(W[d], tk, num);
                v2f tn = v2fma(x2, tk, -tkm1);
                tkm1 = tk; tk = tn;
            }
            const v2f lcu = num * rden;
            v2f ss = (v2f){0.0f, 0.0f};
#pragma unroll
            for (int d = 0; d < DEG; ++d)
                ss += v2sin2pi(lcu * A2[d]);
            const v2f sm = ss * 0.125f;

            // shared-exp: E = e^sm serves both tanh(sm) and sigmoid(sm)
            const v2f E  = v2exp(sm);
            const v2f s  = v2fma(v2rcp(v2fma(E, E, (v2f)(1.0f))),
                                 (v2f)(-1.98f), (v2f)(0.99f)); // 0.99*tanh(sm)
            const v2f si = sm * E * v2rcp(E + 1.0f);           // silu(sm)

            *(unsigned*)(&s_s[r * PITCH2 + fA]) = cvtpk2(s.x, s.y);
            *(unsigned*)(&s_l[r * PITCH2 + fA]) = cvtpk2(si.x, si.y);
        }
    }
    __syncthreads();

    // ------- phase 2: MFMA contraction — transcendental-free ---------------
    const int lane = t & 63;
    const int wave = __builtin_amdgcn_readfirstlane(t >> 6);
    const int n    = lane & 15;          // class col (and A-row m)
    const int q    = lane >> 4;          // quad
    const int ncl  = (n < NC) ? n : (NC - 1);  // junk cols n>=10 never read back
    const int fw   = wave * 128;         // this wave's feature range

    const unsigned short* cb = pk;                          // coeff bf16
    const unsigned short* bb = pk + CBN;                    // base  bf16
    const unsigned short* cbase = cb + (ncl * NF + fw) * KB;

    f32x4 acc0 = {0.f, 0.f, 0.f, 0.f};
    f32x4 acc1 = {0.f, 0.f, 0.f, 0.f};

    // GEMM1: phi @ coeff^T over 128 features = 32 K-tiles, in pairs
#pragma unroll 4
    for (int kp = 0; kp < 16; ++kp) {
        const bfrag b0 = *(const bfrag*)(cbase + (kp * 8 + q) * KB);
        const bfrag b1 = *(const bfrag*)(cbase + (kp * 8 + 4 + q) * KB);

        // s already = 0.99*tanh(summed), straight from LDS
        const float sA = bf2f(s_s[n * PITCH2 + fw + kp * 8 + q]);
        const float sB = bf2f(s_s[n * PITCH2 + fw + kp * 8 + 4 + q]);
        const v2f s  = (v2f){sA, sB};
        const v2f s2 = s + s;
        v2f T[KB];
        {
            v2f tkm1 = (v2f){1.0f, 1.0f}, tk = s;
#pragma unroll
            for (int k = 0; k < KB; ++k) {
                T[k] = tk;
                v2f tn = v2fma(s2, tk, -tkm1);
                tkm1 = tk; tk = tn;
            }
        }
        frag_u fa0, fa1;
#pragma unroll
        for (int i = 0; i < 4; ++i) {
            fa0.u[i] = cvtpk2(T[2 * i].x, T[2 * i + 1].x);
            fa1.u[i] = cvtpk2(T[2 * i].y, T[2 * i + 1].y);
        }
        acc0 = __builtin_amdgcn_mfma_f32_16x16x32_bf16(fa0.s, b0, acc0, 0, 0, 0);
        acc1 = __builtin_amdgcn_mfma_f32_16x16x32_bf16(fa1.s, b1, acc1, 0, 0, 0);
    }

    // GEMM2: silu @ base^T over 128 features = 4 K-tiles.
    // The b128 row-slice of s_l IS the bf16 A-fragment — no conversion.
#pragma unroll
    for (int kt2 = 0; kt2 < 4; ++kt2) {
        const bfrag b = *(const bfrag*)(bb + ncl * NF + fw + kt2 * 32 + q * 8);
        frag_u2 fa;
        fa.v = *(const us8*)(&s_l[n * PITCH2 + fw + kt2 * 32 + q * 8]);
        if (kt2 & 1)
            acc1 = __builtin_amdgcn_mfma_f32_16x16x32_bf16(fa.s, b, acc1, 0, 0, 0);
        else
            acc0 = __builtin_amdgcn_mfma_f32_16x16x32_bf16(fa.s, b, acc0, 0, 0, 0);
    }

    // ------------- cross-wave K-reduction + store ---------------------------
    // D layout: row = q*4+i, col = n. Write all 16 cols; only c<10 read back.
    const f32x4 acc = acc0 + acc1;
#pragma unroll
    for (int i = 0; i < 4; ++i)
        s_red[wave * (RB * 16) + (q * 4 + i) * 16 + n] = acc[i];
    __syncthreads();

    if (t < RB * NC) {
        const int r = t / NC;
        const int c = t - r * NC;
        float v = bias[c];
#pragma unroll
        for (int w = 0; w < NWAVES; ++w)
            v += s_red[w * (RB * 16) + r * 16 + c];
        out[(row0 + r) * NC + c] = v;
    }
}

extern "C" void kernel_launch(void* const* d_in, const int* in_sizes, int n_in,
                              void* d_out, int out_size, void* d_ws, size_t ws_size,
                              hipStream_t stream) {
    const float* X      = (const float*)d_in[0];
    const float* lcu_w  = (const float*)d_in[1];
    const float* alpha  = (const float*)d_in[2];
    const float* coeff  = (const float*)d_in[3];
    const float* base   = (const float*)d_in[4];
    const float* bias   = (const float*)d_in[5];
    float* out = (float*)d_out;
    unsigned short* pk = (unsigned short*)d_ws;   // 92 KB bf16 tables

    prep_kernel<<<(CBN + BBN + 255) / 256, 256, 0, stream>>>(coeff, base, pk);
    qkan_kernel<<<BATCH / RB, NT, 0, stream>>>(X, lcu_w, alpha, pk, bias, out);
}

// Round 10
// 100.081 us; speedup vs baseline: 1.0153x; 1.0079x over previous
//
#include <hip/hip_runtime.h>
#include <hip/hip_bf16.h>

#define BATCH 16384
#define NF    512
#define DEG   8
#define NC    10
#define KB    8

#define RB     16                // rows per block (one MFMA tile)
#define PITCH2 520               // ushort pitch: 1040 B rows (16B-aligned)
#define NT     256               // 4 waves; wave w owns features [w*128, +128)
#define NWAVES 4

#define CBN (NC * NF * KB)       // 40960 packed coeff elems
#define BBN (NC * NF)            // 5120 packed base elems
#define TBN (NF * DEG)           // 4096 per f32 table (wn, a2)

#define INV2PI 0.15915494309189535f
#define LOG2E  1.4426950408889634f

typedef __attribute__((ext_vector_type(2))) float v2f;             // v_pk_*_f32
typedef __attribute__((ext_vector_type(8))) short bfrag;           // 8 bf16
typedef __attribute__((ext_vector_type(8))) unsigned short us8;    // LDS b128
typedef __attribute__((ext_vector_type(4))) float f32x4;           // MFMA C/D

union frag_u  { bfrag s; unsigned u[4]; };
union frag_u2 { us8 v; bfrag s; };

__device__ __forceinline__ v2f v2fma(v2f a, v2f b, v2f c) {
    return __builtin_elementwise_fma(a, b, c);
}
__device__ __forceinline__ v2f v2exp(v2f x) {              // e^x
    v2f a = x * LOG2E;
    v2f r; r.x = __builtin_amdgcn_exp2f(a.x); r.y = __builtin_amdgcn_exp2f(a.y);
    return r;
}
__device__ __forceinline__ v2f v2rcp(v2f x) {
    v2f r; r.x = __builtin_amdgcn_rcpf(x.x); r.y = __builtin_amdgcn_rcpf(x.y);
    return r;
}
__device__ __forceinline__ v2f v2sin2pi(v2f x) {           // sin(2*pi*x)
    v2f r; r.x = __builtin_amdgcn_sinf(x.x); r.y = __builtin_amdgcn_sinf(x.y);
    return r;
}
// 0.99*tanh(x) = 0.99 - 1.98/(exp(2x)+1)
__device__ __forceinline__ v2f v2tanh99(v2f x) {
    v2f e = v2exp(x + x);
    v2f r = v2rcp(e + 1.0f);
    return v2fma(r, (v2f)(-1.98f), (v2f)(0.99f));
}
// f32 pair -> packed bf16 (v_cvt_pk_bf16_f32), lo in low 16 bits
__device__ __forceinline__ unsigned cvtpk2(float lo, float hi) {
    __hip_bfloat162 h = __float22bfloat162_rn(float2{lo, hi});
    unsigned u;
    __builtin_memcpy(&u, &h, sizeof(u));
    return u;
}
__device__ __forceinline__ float bf2f(unsigned short h) {
    unsigned u = ((unsigned)h) << 16;
    return __builtin_bit_cast(float, u);
}
// T_1..T_8 via even/odd split (depth 3 after u), out[k]=T_{k+1}
__device__ __forceinline__ void cheb8(v2f s, v2f T[8]) {
    const v2f s2 = s + s;
    const v2f u  = v2fma(s2, s, (v2f)(-1.0f));   // T2
    const v2f u2 = u + u;
    T[0] = s;
    T[1] = u;
    T[2] = v2fma(u2, s,    -s);                  // T3
    T[3] = v2fma(u2, u,    (v2f)(-1.0f));        // T4
    T[4] = v2fma(u2, T[2], -s);                  // T5
    T[5] = v2fma(u2, T[3], -u);                  // T6
    T[6] = v2fma(u2, T[4], -T[2]);               // T7
    T[7] = v2fma(u2, T[5], -T[3]);               // T8
}

// ---- prep: bf16 tables + folded f32 lcu tables, every launch ---------------
__global__ __launch_bounds__(256) void prep_kernel(
    const float* __restrict__ coeff, const float* __restrict__ base,
    const float* __restrict__ lcu_w, const float* __restrict__ alpha,
    unsigned short* __restrict__ pk,   // bf16: coeff[CBN] then base[BBN]
    float* __restrict__ wn,            // (F,DEG) w / l1norm
    float* __restrict__ a2)            // (F,DEG) alpha / 2pi
{
    const int i = blockIdx.x * 256 + threadIdx.x;
    if (i < CBN)
        pk[i] = (unsigned short)((__builtin_bit_cast(unsigned, coeff[i]) + 0x8000u) >> 16);
    else if (i < CBN + BBN)
        pk[i] = (unsigned short)((__builtin_bit_cast(unsigned, base[i - CBN]) + 0x8000u) >> 16);
    if (i < NF) {
        float w[DEG], d = 1e-8f;
#pragma unroll
        for (int k = 0; k < DEG; ++k) { w[k] = lcu_w[i * DEG + k]; d += fabsf(w[k]); }
        const float rd = 1.0f / d;
#pragma unroll
        for (int k = 0; k < DEG; ++k) {
            wn[i * DEG + k] = w[k] * rd;
            a2[i * DEG + k] = alpha[i * DEG + k] * INV2PI;
        }
    }
}

__global__ __launch_bounds__(NT, 4) void qkan_kernel(
    const float* __restrict__ X,        // (B, F)
    const float* __restrict__ wn,       // (F, DEG) folded lcu weights
    const float* __restrict__ a2,       // (F, DEG) folded phases
    const unsigned short* __restrict__ pk,  // bf16: coeff[CBN] then base[BBN]
    const float* __restrict__ bias,     // (C)
    float* __restrict__ out)            // (B, C)
{
    __shared__ unsigned short s_s[RB * PITCH2];     // 16.6 KB: 0.99*tanh(summed)
    __shared__ unsigned short s_l[RB * PITCH2];     // 16.6 KB: silu(summed)
    __shared__ float s_red[NWAVES * RB * 16];       // 4 KB: cross-wave partials

    const int t    = threadIdx.x;
    const int row0 = blockIdx.x * RB;

    // ------- phase 1: elementwise -> s(b,f), silu(b,f) into LDS (bf16) ------
    // thread owns feature pair t*2, all 16 rows; tables are pure loads now.
    {
        const int fA = t * 2;
        v2f W[DEG], A[DEG];
        {
            const float4 w0 = *(const float4*)(wn + fA * DEG);
            const float4 w1 = *(const float4*)(wn + fA * DEG + 4);
            const float4 w2 = *(const float4*)(wn + fA * DEG + 8);
            const float4 w3 = *(const float4*)(wn + fA * DEG + 12);
            const float4 a0 = *(const float4*)(a2 + fA * DEG);
            const float4 a1 = *(const float4*)(a2 + fA * DEG + 4);
            const float4 a3 = *(const float4*)(a2 + fA * DEG + 8);
            const float4 a4 = *(const float4*)(a2 + fA * DEG + 12);
            const float wf0[8] = {w0.x,w0.y,w0.z,w0.w,w1.x,w1.y,w1.z,w1.w};
            const float wf1[8] = {w2.x,w2.y,w2.z,w2.w,w3.x,w3.y,w3.z,w3.w};
            const float af0[8] = {a0.x,a0.y,a0.z,a0.w,a1.x,a1.y,a1.z,a1.w};
            const float af1[8] = {a3.x,a3.y,a3.z,a3.w,a4.x,a4.y,a4.z,a4.w};
#pragma unroll
            for (int d = 0; d < DEG; ++d) {
                W[d] = (v2f){wf0[d], wf1[d]};
                A[d] = (v2f){af0[d], af1[d]};
            }
        }

#pragma unroll 4
        for (int r = 0; r < RB; ++r) {
            const v2f xv = *(const v2f*)(X + (row0 + r) * NF + fA);
            const v2f x  = v2tanh99(xv);
            v2f T[8];
            cheb8(x, T);
            // LCU dot (den pre-folded): two independent chains
            v2f n0 = W[0] * T[0];
            v2f n1 = W[1] * T[1];
            n0 = v2fma(W[2], T[2], n0);  n1 = v2fma(W[3], T[3], n1);
            n0 = v2fma(W[4], T[4], n0);  n1 = v2fma(W[5], T[5], n1);
            n0 = v2fma(W[6], T[6], n0);  n1 = v2fma(W[7], T[7], n1);
            const v2f lcu = n0 + n1;
            // 8 sins, binary-tree sum (depth 3)
            v2f sn[8];
#pragma unroll
            for (int d = 0; d < DEG; ++d)
                sn[d] = v2sin2pi(lcu * A[d]);
            const v2f ss = ((sn[0] + sn[1]) + (sn[2] + sn[3]))
                         + ((sn[4] + sn[5]) + (sn[6] + sn[7]));
            const v2f sm = ss * 0.125f;

            // shared-exp: E = e^sm serves both tanh(sm) and sigmoid(sm)
            const v2f E  = v2exp(sm);
            const v2f s  = v2fma(v2rcp(v2fma(E, E, (v2f)(1.0f))),
                                 (v2f)(-1.98f), (v2f)(0.99f)); // 0.99*tanh(sm)
            const v2f si = sm * E * v2rcp(E + 1.0f);           // silu(sm)

            *(unsigned*)(&s_s[r * PITCH2 + fA]) = cvtpk2(s.x, s.y);
            *(unsigned*)(&s_l[r * PITCH2 + fA]) = cvtpk2(si.x, si.y);
        }
    }
    __syncthreads();

    // ------- phase 2: MFMA contraction — transcendental-free ---------------
    const int lane = t & 63;
    const int wave = __builtin_amdgcn_readfirstlane(t >> 6);
    const int n    = lane & 15;          // class col (and A-row m)
    const int q    = lane >> 4;          // quad
    const int ncl  = (n < NC) ? n : (NC - 1);  // junk cols n>=10 never read back
    const int fw   = wave * 128;         // this wave's feature range

    const unsigned short* cb = pk;                          // coeff bf16
    const unsigned short* bb = pk + CBN;                    // base  bf16
    const unsigned short* cbase = cb + (ncl * NF + fw) * KB;

    f32x4 acc0 = {0.f, 0.f, 0.f, 0.f};
    f32x4 acc1 = {0.f, 0.f, 0.f, 0.f};

    // GEMM1: phi @ coeff^T over 128 features = 32 K-tiles, in pairs
#pragma unroll 4
    for (int kp = 0; kp < 16; ++kp) {
        const bfrag b0 = *(const bfrag*)(cbase + (kp * 8 + q) * KB);
        const bfrag b1 = *(const bfrag*)(cbase + (kp * 8 + 4 + q) * KB);

        const float sA = bf2f(s_s[n * PITCH2 + fw + kp * 8 + q]);
        const float sB = bf2f(s_s[n * PITCH2 + fw + kp * 8 + 4 + q]);
        v2f T[8];
        cheb8((v2f){sA, sB}, T);
        frag_u fa0, fa1;
#pragma unroll
        for (int i = 0; i < 4; ++i) {
            fa0.u[i] = cvtpk2(T[2 * i].x, T[2 * i + 1].x);
            fa1.u[i] = cvtpk2(T[2 * i].y, T[2 * i + 1].y);
        }
        acc0 = __builtin_amdgcn_mfma_f32_16x16x32_bf16(fa0.s, b0, acc0, 0, 0, 0);
        acc1 = __builtin_amdgcn_mfma_f32_16x16x32_bf16(fa1.s, b1, acc1, 0, 0, 0);
    }

    // GEMM2: silu @ base^T over 128 features = 4 K-tiles.
    // The b128 row-slice of s_l IS the bf16 A-fragment — no conversion.
#pragma unroll
    for (int kt2 = 0; kt2 < 4; ++kt2) {
        const bfrag b = *(const bfrag*)(bb + ncl * NF + fw + kt2 * 32 + q * 8);
        frag_u2 fa;
        fa.v = *(const us8*)(&s_l[n * PITCH2 + fw + kt2 * 32 + q * 8]);
        if (kt2 & 1)
            acc1 = __builtin_amdgcn_mfma_f32_16x16x32_bf16(fa.s, b, acc1, 0, 0, 0);
        else
            acc0 = __builtin_amdgcn_mfma_f32_16x16x32_bf16(fa.s, b, acc0, 0, 0, 0);
    }

    // ------------- cross-wave K-reduction + store ---------------------------
    const f32x4 acc = acc0 + acc1;
#pragma unroll
    for (int i = 0; i < 4; ++i)
        s_red[wave * (RB * 16) + (q * 4 + i) * 16 + n] = acc[i];
    __syncthreads();

    if (t < RB * NC) {
        const int r = t / NC;
        const int c = t - r * NC;
        float v = bias[c];
#pragma unroll
        for (int w = 0; w < NWAVES; ++w)
            v += s_red[w * (RB * 16) + r * 16 + c];
        out[(row0 + r) * NC + c] = v;
    }
}

extern "C" void kernel_launch(void* const* d_in, const int* in_sizes, int n_in,
                              void* d_out, int out_size, void* d_ws, size_t ws_size,
                              hipStream_t stream) {
    const float* X      = (const float*)d_in[0];
    const float* lcu_w  = (const float*)d_in[1];
    const float* alpha  = (const float*)d_in[2];
    const float* coeff  = (const float*)d_in[3];
    const float* base   = (const float*)d_in[4];
    const float* bias   = (const float*)d_in[5];
    float* out = (float*)d_out;
    unsigned short* pk = (unsigned short*)d_ws;         // 92 KB bf16 tables
    float* wn = (float*)(pk + CBN + BBN);               // 16 KB folded weights
    float* a2 = wn + TBN;                               // 16 KB folded phases

    prep_kernel<<<(CBN + BBN + 255) / 256, 256, 0, stream>>>(
        coeff, base, lcu_w, alpha, pk, wn, a2);
    qkan_kernel<<<BATCH / RB, NT, 0, stream>>>(X, wn, a2, pk, bias, out);
}